// Round 1
// baseline (535.666 us; speedup 1.0000x reference)
//
#include <hip/hip_runtime.h>

using f32x4 = float    __attribute__((ext_vector_type(4)));
using f16x8 = _Float16 __attribute__((ext_vector_type(8)));
using f16x4 = _Float16 __attribute__((ext_vector_type(4)));

__device__ __forceinline__ void gload_lds16(const void* g, void* l) {
    __builtin_amdgcn_global_load_lds(
        (__attribute__((address_space(1))) void*)(void*)g,
        (__attribute__((address_space(3))) void*)l, 16, 0, 0);
}

// BK=32 swizzle (validated R3/R6/R7), rows 64B apart, 4 slots of 16B:
//   stage: lane seg=lane&3 row r16=lane>>2 pulls k-seg ((seg-(r16>>1))&3)
//   read:  k-seg `quad` of row lrow at slot ((quad+(lrow>>1))&3)
// BK=64 swizzle: rows 128B apart, 8 slots of 16B, rotate by row:
//   stage: lane seg=lane&7 row r8=lane>>3 pulls k-seg ((seg-r8)&7)
//   read:  k-seg (quad+4*ks) of row lrow at slot ((quad+4*ks+lrow)&7)

// ---------------- fp32 -> fp16 elementwise convert (8 elems/thread) ---------
__global__ __launch_bounds__(256) void k_cvt_x(
    const float* __restrict__ in, _Float16* __restrict__ out) {
    int i = (blockIdx.x * 256 + threadIdx.x) * 8;
    f32x4 a = *(const f32x4*)(in + i);
    f32x4 b = *(const f32x4*)(in + i + 4);
    f16x8 o;
    #pragma unroll
    for (int j = 0; j < 4; ++j) { o[j] = (_Float16)a[j]; o[j + 4] = (_Float16)b[j]; }
    *(f16x8*)(out + i) = o;
}

// ---------------- fp32 in [R][C] -> fp16 out[c][r] (convert + transpose) ----
__global__ __launch_bounds__(256) void k_cvtT(
    const float* __restrict__ in, _Float16* __restrict__ out, int R, int C) {
    __shared__ _Float16 tile[32][33];
    int c0 = blockIdx.x * 32, r0 = blockIdx.y * 32;
    int tx = threadIdx.x & 31, ty = threadIdx.x >> 5;
    #pragma unroll
    for (int i = ty; i < 32; i += 8)
        tile[i][tx] = (_Float16)in[(size_t)(r0 + i) * C + c0 + tx];
    __syncthreads();
    #pragma unroll
    for (int i = ty; i < 32; i += 8)
        out[(size_t)(c0 + i) * R + r0 + tx] = tile[tx][i];
}

// ------- fused GEMM1: Wh/Ws pair + tanh + transposed Wh output (R7-valid) ---
__global__ __launch_bounds__(512, 4) void k_gemm1f(
    const _Float16* __restrict__ A, const _Float16* __restrict__ Bt,
    _Float16* __restrict__ Whh, _Float16* __restrict__ T,
    _Float16* __restrict__ WhT,
    const float* __restrict__ aw, const float* __restrict__ ab) {
    __shared__ _Float16 As[128 * 32];
    __shared__ _Float16 B0s[64 * 32];
    __shared__ _Float16 B1s[64 * 32];
    const float bias = aw[0] + ab[0];
    const int row0 = blockIdx.y * 128, col0 = blockIdx.x * 64;
    const int tid = threadIdx.x, w = tid >> 6, lane = tid & 63;
    const int wm = w >> 2, wn = w & 3;
    const int lrow = lane & 15, quad = lane >> 4;
    const int r16 = lane >> 2;
    const int kc = (((lane & 3) - ((lane >> 3) & 3)) & 3) * 8;
    const int sq = ((quad + ((lrow >> 1) & 3)) & 3) * 8;
    f32x4 acc0[4] = {}, acc1[4] = {};
    for (int k0 = 0; k0 < 512; k0 += 32) {
        gload_lds16(A + (size_t)(row0 + w * 16 + r16) * 512 + k0 + kc,
                    As + w * 512);
        if (w < 4)
            gload_lds16(Bt + (size_t)(col0 + w * 16 + r16) * 512 + k0 + kc,
                        B0s + w * 512);
        else
            gload_lds16(Bt + (size_t)(col0 + 512 + (w - 4) * 16 + r16) * 512 + k0 + kc,
                        B1s + (w - 4) * 512);
        __syncthreads();
        f16x8 af[4], b0, b1;
        #pragma unroll
        for (int i = 0; i < 4; ++i)
            af[i] = *(const f16x8*)(As + (wm * 64 + i * 16 + lrow) * 32 + sq);
        b0 = *(const f16x8*)(B0s + (wn * 16 + lrow) * 32 + sq);
        b1 = *(const f16x8*)(B1s + (wn * 16 + lrow) * 32 + sq);
        #pragma unroll
        for (int mi = 0; mi < 4; ++mi) {
            acc0[mi] = __builtin_amdgcn_mfma_f32_16x16x32_f16(af[mi], b0, acc0[mi], 0, 0, 0);
            acc1[mi] = __builtin_amdgcn_mfma_f32_16x16x32_f16(af[mi], b1, acc1[mi], 0, 0, 0);
        }
        __syncthreads();
    }
    const int col = col0 + wn * 16 + lrow;
    #pragma unroll
    for (int mi = 0; mi < 4; ++mi) {
        int rowb = row0 + wm * 64 + mi * 16 + quad * 4;
        f16x4 pw;
        #pragma unroll
        for (int r = 0; r < 4; ++r) {
            float wh = acc0[mi][r];
            float tt = tanhf(wh + acc1[mi][r] + bias);
            Whh[(size_t)(rowb + r) * 512 + col] = (_Float16)wh;
            T[(size_t)(rowb + r) * 512 + col]   = (_Float16)tt;
            pw[r] = (_Float16)wh;
        }
        *(f16x4*)(WhT + (size_t)col * 8192 + rowb) = pw;
    }
}

// ---------------- GEMM2: S = T @ Whh^T  (BM=256, BN=128, BK=64) -------------
// Epilogue additionally emits per-(row, 64-col-block) softmax partials:
//   msP[cb*8192+row] = max over 64 cols (of the fp16-quantized s values)
//   lsP[cb*8192+row] = sum exp(s - m_b)
// cb = blockIdx.x*2 + wn  (128 col-blocks of 64 cols). 16-lane shfl reduce.
__global__ __launch_bounds__(512, 4) void k_gemm2(
    const _Float16* __restrict__ A,      // T [8192,512]
    const _Float16* __restrict__ Bt,     // Whh [8192,512]
    _Float16* __restrict__ Cp,           // S [8192,8192]
    float* __restrict__ msP, float* __restrict__ lsP) {
    __shared__ _Float16 As[256 * 64];
    __shared__ _Float16 Bs[128 * 64];
    const int row0 = blockIdx.y * 256, col0 = blockIdx.x * 128;
    const int tid = threadIdx.x, w = tid >> 6, lane = tid & 63;
    const int wm = w >> 1, wn = w & 1;
    const int lrow = lane & 15, quad = lane >> 4;
    const int r8 = lane >> 3;                       // row within 8-row chunk
    const int kc8 = (((lane & 7) - r8) & 7) * 8;    // staged source k-seg
    f32x4 acc[4][4] = {};
    for (int k0 = 0; k0 < 512; k0 += 64) {
        #pragma unroll
        for (int i = 0; i < 6; ++i) {
            int c = w + i * 8;                      // 48 chunks
            if (c < 32) {
                gload_lds16(A + (size_t)(row0 + c * 8 + r8) * 512 + k0 + kc8,
                            As + c * 512);
            } else {
                int c2 = c - 32;
                gload_lds16(Bt + (size_t)(col0 + c2 * 8 + r8) * 512 + k0 + kc8,
                            Bs + c2 * 512);
            }
        }
        __syncthreads();
        #pragma unroll
        for (int ks = 0; ks < 2; ++ks) {
            const int sl = ((quad + ks * 4 + lrow) & 7) * 8;
            f16x8 af[4], bf[4];
            #pragma unroll
            for (int i = 0; i < 4; ++i)
                af[i] = *(const f16x8*)(As + (wm * 64 + i * 16 + lrow) * 64 + sl);
            #pragma unroll
            for (int i = 0; i < 4; ++i)
                bf[i] = *(const f16x8*)(Bs + (wn * 64 + i * 16 + lrow) * 64 + sl);
            #pragma unroll
            for (int mi = 0; mi < 4; ++mi)
                #pragma unroll
                for (int ni = 0; ni < 4; ++ni)
                    acc[mi][ni] = __builtin_amdgcn_mfma_f32_16x16x32_f16(
                        af[mi], bf[ni], acc[mi][ni], 0, 0, 0);
        }
        __syncthreads();
    }
    const int cb = blockIdx.x * 2 + wn;
    #pragma unroll
    for (int mi = 0; mi < 4; ++mi) {
        #pragma unroll
        for (int r = 0; r < 4; ++r) {
            const int row = row0 + wm * 64 + mi * 16 + quad * 4 + r;
            float vq[4]; float sm = -3.0e38f;
            #pragma unroll
            for (int ni = 0; ni < 4; ++ni) {
                _Float16 hv = (_Float16)acc[mi][ni][r];
                Cp[(size_t)row * 8192 + col0 + wn * 64 + ni * 16 + lrow] = hv;
                vq[ni] = (float)hv;
                sm = fmaxf(sm, vq[ni]);
            }
            #pragma unroll
            for (int off = 1; off < 16; off <<= 1)
                sm = fmaxf(sm, __shfl_xor(sm, off));
            float ls = 0.f;
            #pragma unroll
            for (int ni = 0; ni < 4; ++ni) ls += __expf(vq[ni] - sm);
            #pragma unroll
            for (int off = 1; off < 16; off <<= 1)
                ls += __shfl_xor(ls, off);
            if (lrow == 0) {
                msP[(size_t)cb * 8192 + row] = sm;
                lsP[(size_t)cb * 8192 + row] = ls;
            }
        }
    }
}

// -------- combine 128 per-block softmax partials per row (online merge) -----
// 8 independent chains to hide load latency; grid 128 x 64 threads.
__global__ __launch_bounds__(64) void k_rowstats(
    const float* __restrict__ ms, const float* __restrict__ ls,
    float* __restrict__ mrow, float* __restrict__ rl) {
    const int row = blockIdx.x * 64 + threadIdx.x;
    float m[8], l[8];
    #pragma unroll
    for (int k = 0; k < 8; ++k) { m[k] = -3.0e38f; l[k] = 0.f; }
    for (int j = 0; j < 16; ++j) {
        #pragma unroll
        for (int k = 0; k < 8; ++k) {
            const int cb = k * 16 + j;
            float mb = ms[(size_t)cb * 8192 + row];
            float lb = ls[(size_t)cb * 8192 + row];
            float mn = fmaxf(m[k], mb);
            l[k] = l[k] * __expf(m[k] - mn) + lb * __expf(mb - mn);
            m[k] = mn;
        }
    }
    float M = m[0];
    #pragma unroll
    for (int k = 1; k < 8; ++k) M = fmaxf(M, m[k]);
    float L = 0.f;
    #pragma unroll
    for (int k = 0; k < 8; ++k) L += l[k] * __expf(m[k] - M);
    mrow[row] = M * 1.44269504f;   // pre-scaled by log2(e) for exp2 in gemm3
    rl[row]   = 1.f / L;
}

// ------- GEMM3: part[z] = exp(S - m)[:, zchunk] @ Wh[zchunk, :]  (BK=64) ----
// A (=S) is reg-staged: load f16x8 from swizzled global addr, apply
// p = exp2(s*log2e - mrow) elementwise, ds_write_b128 to the SAME linear LDS
// slot gload_lds would have used -> layout identical to validated path.
// B stays global_load_lds. Normalization 1/l applied later in reduce_stats.
__global__ __launch_bounds__(512, 4) void k_gemm3(
    const _Float16* __restrict__ A,      // S [8192][8192] raw scores fp16
    const _Float16* __restrict__ Bt,     // WhT [512][8192]
    const float* __restrict__ mrow,      // [8192] rowmax * log2e
    float* __restrict__ Cp) {            // partials [4][8192][512]
    __shared__ _Float16 As[128 * 64];
    __shared__ _Float16 Bs[256 * 64];
    const int row0 = blockIdx.y * 128, col0 = blockIdx.x * 256;
    const size_t zoff = (size_t)blockIdx.z * 2048;
    Cp += (size_t)blockIdx.z * ((size_t)8192 * 512);
    const int tid = threadIdx.x, w = tid >> 6, lane = tid & 63;
    const int wm = w >> 2, wn = w & 3;
    const int lrow = lane & 15, quad = lane >> 4;
    const int r8 = lane >> 3;
    const int kc8 = (((lane & 7) - r8) & 7) * 8;
    const int rowA0 = row0 + w * 8 + r8;            // chunk c = w
    const int rowA1 = row0 + (w + 8) * 8 + r8;      // chunk c = w + 8
    const float ms0 = mrow[rowA0];
    const float ms1 = mrow[rowA1];
    f32x4 acc[4][4] = {};
    for (int k0 = 0; k0 < 2048; k0 += 64) {
        // A chunks: reg-staged with on-the-fly exp
        f16x8 h0 = *(const f16x8*)(A + (size_t)rowA0 * 8192 + zoff + k0 + kc8);
        f16x8 h1 = *(const f16x8*)(A + (size_t)rowA1 * 8192 + zoff + k0 + kc8);
        f16x8 q0, q1;
        #pragma unroll
        for (int j = 0; j < 8; ++j) {
            q0[j] = (_Float16)exp2f(fmaf((float)h0[j], 1.44269504f, -ms0));
            q1[j] = (_Float16)exp2f(fmaf((float)h1[j], 1.44269504f, -ms1));
        }
        *(f16x8*)(As + w * 512 + lane * 8)       = q0;
        *(f16x8*)(As + (w + 8) * 512 + lane * 8) = q1;
        // B chunks: async gload as before (32 chunks across 8 waves)
        #pragma unroll
        for (int i = 2; i < 6; ++i) {
            int c2 = w + i * 8 - 16;
            gload_lds16(Bt + (size_t)(col0 + c2 * 8 + r8) * 8192 + zoff + k0 + kc8,
                        Bs + c2 * 512);
        }
        __syncthreads();
        #pragma unroll
        for (int ks = 0; ks < 2; ++ks) {
            const int sl = ((quad + ks * 4 + lrow) & 7) * 8;
            f16x8 af[4], bf[4];
            #pragma unroll
            for (int i = 0; i < 4; ++i)
                af[i] = *(const f16x8*)(As + (wm * 64 + i * 16 + lrow) * 64 + sl);
            #pragma unroll
            for (int i = 0; i < 4; ++i)
                bf[i] = *(const f16x8*)(Bs + (wn * 64 + i * 16 + lrow) * 64 + sl);
            #pragma unroll
            for (int mi = 0; mi < 4; ++mi)
                #pragma unroll
                for (int ni = 0; ni < 4; ++ni)
                    acc[mi][ni] = __builtin_amdgcn_mfma_f32_16x16x32_f16(
                        af[mi], bf[ni], acc[mi][ni], 0, 0, 0);
        }
        __syncthreads();
    }
    #pragma unroll
    for (int mi = 0; mi < 4; ++mi) {
        #pragma unroll
        for (int ni = 0; ni < 4; ++ni) {
            int col = col0 + wn * 64 + ni * 16 + lrow;
            #pragma unroll
            for (int r = 0; r < 4; ++r) {
                int row = row0 + wm * 64 + mi * 16 + quad * 4 + r;
                Cp[(size_t)row * 512 + col] = acc[mi][ni][r];
            }
        }
    }
}

// ------- fused: outf = rl*(sum part[0..3]) + X, plus column stats atomics ---
__global__ __launch_bounds__(256) void k_reduce_stats(
    const float* __restrict__ part, const float* __restrict__ X,
    const float* __restrict__ rl,
    float* __restrict__ outf, float* __restrict__ cs, float* __restrict__ cq) {
    const int t = threadIdx.x;
    const int r0 = blockIdx.x * 32;
    constexpr size_t PS = (size_t)8192 * 512;
    float s0 = 0, q0 = 0, s1 = 0, q1 = 0;
    for (int r = 0; r < 32; ++r) {
        size_t base = (size_t)(r0 + r) * 512;
        float rlv = rl[r0 + r];
        float a = (part[base + t] + part[PS + base + t]
                + part[2 * PS + base + t] + part[3 * PS + base + t]) * rlv
                + X[base + t];
        float b = (part[base + t + 256] + part[PS + base + t + 256]
                + part[2 * PS + base + t + 256] + part[3 * PS + base + t + 256]) * rlv
                + X[base + t + 256];
        outf[base + t] = a;       outf[base + t + 256] = b;
        s0 += a; q0 += a * a; s1 += b; q1 += b * b;
    }
    atomicAdd(&cs[t], s0);       atomicAdd(&cq[t], q0);
    atomicAdd(&cs[t + 256], s1); atomicAdd(&cq[t + 256], q1);
}

// ---------------- batchnorm (no affine) + leaky relu -> fp32 ----------------
__global__ __launch_bounds__(256) void k_bn_lrelu(
    const float* __restrict__ outf, const float* __restrict__ colsum,
    const float* __restrict__ colsq, float* __restrict__ out) {
    int i = blockIdx.x * 256 + threadIdx.x;
    int c = i & 511;
    constexpr float rN = 1.f / 8192.f;
    float mean = colsum[c] * rN;
    float var  = colsq[c] * rN - mean * mean;
    float y = (outf[i] - mean) * rsqrtf(var + 1e-5f);
    y = (y >= 0.f) ? y : 0.01f * y;
    out[i] = y;
}

extern "C" void kernel_launch(void* const* d_in, const int* in_sizes, int n_in,
                              void* d_out, int out_size, void* d_ws, size_t ws_size,
                              hipStream_t stream) {
    const float* X  = (const float*)d_in[0];  // [8192,512] fp32
    // d_in[1] = adj, unused
    const float* W  = (const float*)d_in[2];  // [512,1024] fp32
    const float* aw = (const float*)d_in[3];
    const float* ab = (const float*)d_in[4];
    float* out = (float*)d_out;               // [8192,512] fp32

    char* ws = (char*)d_ws;
    _Float16* Xh   = (_Float16*)(ws + 0x0);          //   8 MB [8192,512]
    _Float16* Wt   = (_Float16*)(ws + 0x800000);     //   1 MB W^T [1024,512]
    _Float16* T    = (_Float16*)(ws + 0x900000);     //   8 MB [8192,512]
    _Float16* Whh  = (_Float16*)(ws + 0x1100000);    //   8 MB [8192,512]
    _Float16* WhT  = (_Float16*)(ws + 0x1900000);    //   8 MB [512,8192]
    _Float16* S    = (_Float16*)(ws + 0x2100000);    // 128 MB [8192,8192] fp16
    float*    outf = (float*)   (ws + 0xA100000);    //  16 MB [8192,512] fp32
    float*    part = (float*)   (ws + 0xB100000);    //  64 MB 4x[8192,512] fp32
    // msP/lsP alias the (not-yet-written) part buffer; consumed by k_rowstats
    // strictly before k_gemm3 writes part.
    float*    msP  = (float*)   (ws + 0xB100000);    //   4 MB [128][8192]
    float*    lsP  = (float*)   (ws + 0xB500000);    //   4 MB [128][8192]
    float*    cs   = (float*)   (ws + 0xF100000);    //   2 KB
    float*    cq   = (float*)   (ws + 0xF100800);    //   2 KB
    float*    mrow = (float*)   (ws + 0xF101000);    //  32 KB [8192] max*log2e
    float*    rl   = (float*)   (ws + 0xF109000);    //  32 KB [8192] 1/l

    // stats accumulators zeroed up-front
    hipMemsetAsync(cs, 0, 4096, stream);
    // 0. Xh = fp16(X);  Wt = fp16(W^T)
    k_cvt_x<<<dim3((8192 * 512) / 2048), 256, 0, stream>>>(X, Xh);
    k_cvtT<<<dim3(1024 / 32, 512 / 32), 256, 0, stream>>>(W, Wt, 512, 1024);
    // 1. fused: Whh/T/WhT from Xh @ Wt (both halves + tanh + transpose)
    k_gemm1f<<<dim3(8, 64), 512, 0, stream>>>(Xh, Wt, Whh, T, WhT, aw, ab);
    // 2. S = T @ Whh^T  + per-block softmax partials (m_b, l_b)
    k_gemm2<<<dim3(64, 32), 512, 0, stream>>>(T, Whh, S, msP, lsP);
    // 3. combine partials -> mrow (max*log2e), rl (1/sumexp)   [tiny]
    k_rowstats<<<dim3(128), 64, 0, stream>>>(msP, lsP, mrow, rl);
    // 4. part[z] = exp(S - m)[:, z-chunk] @ Wh[z-chunk, :]
    k_gemm3<<<dim3(2, 64, 4), 512, 0, stream>>>(S, WhT, mrow, part);
    // 5. outf = rl*sum(part) + X, fused column stats (256 blocks)
    k_reduce_stats<<<dim3(256), 256, 0, stream>>>(part, X, rl, outf, cs, cq);
    // 6. batchnorm + leaky relu
    k_bn_lrelu<<<dim3((8192 * 512) / 256), 256, 0, stream>>>(outf, cs, cq, out);
}